// Round 2
// baseline (1254.325 us; speedup 1.0000x reference)
//
#include <hip/hip_runtime.h>

using bf16   = __bf16;
using bf16x8 = __attribute__((ext_vector_type(8))) __bf16;
using f32x4  = __attribute__((ext_vector_type(4))) float;

constexpr int BATCH = 32;
constexpr int NQ    = 1024;
constexpr int MK    = 1024;
constexpr int DIM   = 1024;
constexpr int DQK   = 128;
constexpr int LP    = 40;   // LDS bf16 pitch for 32-wide k tiles (pad 8)

// ---- weight transpose + bf16 split: W[R][C] fp32 -> WT_hi/lo [C][R] bf16 ----
__global__ void transpose_split(const float* __restrict__ in, bf16* __restrict__ hiT,
                                bf16* __restrict__ loT, int R, int C) {
    int idx = blockIdx.x * 256 + threadIdx.x;
    if (idx >= R * C) return;
    int r = idx / C, c = idx - r * C;
    float v = in[idx];
    bf16 h = (bf16)v;
    hiT[(size_t)c * R + r] = h;
    loT[(size_t)c * R + r] = (bf16)(v - (float)h);
}

__global__ void transpose_cvt(const float* __restrict__ in, bf16* __restrict__ outT,
                              int R, int C) {
    int idx = blockIdx.x * 256 + threadIdx.x;
    if (idx >= R * C) return;
    int r = idx / C, c = idx - r * C;
    outT[(size_t)c * R + r] = (bf16)in[idx];
}

// ---- split-precision GEMM: C = A(fp32) * BT^T + bias, emit C as bf16 hi+lo ----
// A [M][K] fp32, BhT/BlT [N][K] bf16 (pre-split), 64x64 tile, BK=32, 4 waves.
__global__ __launch_bounds__(256) void gemm_bt_split(const float* __restrict__ A,
                                                     const bf16* __restrict__ BhT,
                                                     const bf16* __restrict__ BlT,
                                                     const float* __restrict__ bias,
                                                     bf16* __restrict__ Chi,
                                                     bf16* __restrict__ Clo,
                                                     int M, int N, int K) {
    __shared__ alignas(16) bf16 Ah[64 * LP];
    __shared__ alignas(16) bf16 Al[64 * LP];
    __shared__ alignas(16) bf16 Bh[64 * LP];
    __shared__ alignas(16) bf16 Bl[64 * LP];
    const int tid = threadIdx.x;
    const int wv = tid >> 6, ln = tid & 63, q = ln >> 4, l16 = ln & 15;
    const int m0 = blockIdx.x * 64, n0 = blockIdx.y * 64;
    const int sr = tid >> 2, sc = (tid & 3) * 8;

    f32x4 acc[4] = {{0,0,0,0},{0,0,0,0},{0,0,0,0},{0,0,0,0}};

    for (int k0 = 0; k0 < K; k0 += 32) {
        const float* ap = A + (size_t)(m0 + sr) * K + k0 + sc;
        f32x4 a0 = *reinterpret_cast<const f32x4*>(ap);
        f32x4 a1 = *reinterpret_cast<const f32x4*>(ap + 4);
        bf16x8 hv, lv;
#pragma unroll
        for (int e = 0; e < 8; ++e) {
            float v = (e < 4) ? a0[e] : a1[e - 4];
            bf16 h = (bf16)v;
            hv[e] = h;
            lv[e] = (bf16)(v - (float)h);
        }
        *reinterpret_cast<bf16x8*>(&Ah[sr * LP + sc]) = hv;
        *reinterpret_cast<bf16x8*>(&Al[sr * LP + sc]) = lv;
        *reinterpret_cast<bf16x8*>(&Bh[sr * LP + sc]) =
            *reinterpret_cast<const bf16x8*>(BhT + (size_t)(n0 + sr) * K + k0 + sc);
        *reinterpret_cast<bf16x8*>(&Bl[sr * LP + sc]) =
            *reinterpret_cast<const bf16x8*>(BlT + (size_t)(n0 + sr) * K + k0 + sc);
        __syncthreads();
        bf16x8 afh = *reinterpret_cast<const bf16x8*>(&Ah[(wv * 16 + l16) * LP + q * 8]);
        bf16x8 afl = *reinterpret_cast<const bf16x8*>(&Al[(wv * 16 + l16) * LP + q * 8]);
#pragma unroll
        for (int t = 0; t < 4; ++t) {
            bf16x8 bfh = *reinterpret_cast<const bf16x8*>(&Bh[(t * 16 + l16) * LP + q * 8]);
            bf16x8 bfl = *reinterpret_cast<const bf16x8*>(&Bl[(t * 16 + l16) * LP + q * 8]);
            acc[t] = __builtin_amdgcn_mfma_f32_16x16x32_bf16(afh, bfh, acc[t], 0, 0, 0);
            acc[t] = __builtin_amdgcn_mfma_f32_16x16x32_bf16(afh, bfl, acc[t], 0, 0, 0);
            acc[t] = __builtin_amdgcn_mfma_f32_16x16x32_bf16(afl, bfh, acc[t], 0, 0, 0);
        }
        __syncthreads();
    }
#pragma unroll
    for (int t = 0; t < 4; ++t) {
        const int col = n0 + t * 16 + l16;
        const float bb = bias[col];
#pragma unroll
        for (int r = 0; r < 4; ++r) {
            const int row = m0 + wv * 16 + q * 4 + r;
            float v = acc[t][r] + bb;
            bf16 h = (bf16)v;
            Chi[(size_t)row * N + col] = h;
            Clo[(size_t)row * N + col] = (bf16)(v - (float)h);
        }
    }
}

// ---- plain bf16 GEMM (hi-only): V = ctx(fp32->bf16) * WvT^T + bias, bf16 out ----
__global__ __launch_bounds__(256) void gemm_bt_plain(const float* __restrict__ A,
                                                     const bf16* __restrict__ BT,
                                                     const float* __restrict__ bias,
                                                     bf16* __restrict__ C,
                                                     int M, int N, int K) {
    __shared__ alignas(16) bf16 Ah[64 * LP];
    __shared__ alignas(16) bf16 Bh[64 * LP];
    const int tid = threadIdx.x;
    const int wv = tid >> 6, ln = tid & 63, q = ln >> 4, l16 = ln & 15;
    const int m0 = blockIdx.x * 64, n0 = blockIdx.y * 64;
    const int sr = tid >> 2, sc = (tid & 3) * 8;

    f32x4 acc[4] = {{0,0,0,0},{0,0,0,0},{0,0,0,0},{0,0,0,0}};

    for (int k0 = 0; k0 < K; k0 += 32) {
        const float* ap = A + (size_t)(m0 + sr) * K + k0 + sc;
        f32x4 a0 = *reinterpret_cast<const f32x4*>(ap);
        f32x4 a1 = *reinterpret_cast<const f32x4*>(ap + 4);
        bf16x8 hv;
#pragma unroll
        for (int e = 0; e < 8; ++e) hv[e] = (bf16)((e < 4) ? a0[e] : a1[e - 4]);
        *reinterpret_cast<bf16x8*>(&Ah[sr * LP + sc]) = hv;
        *reinterpret_cast<bf16x8*>(&Bh[sr * LP + sc]) =
            *reinterpret_cast<const bf16x8*>(BT + (size_t)(n0 + sr) * K + k0 + sc);
        __syncthreads();
        bf16x8 af = *reinterpret_cast<const bf16x8*>(&Ah[(wv * 16 + l16) * LP + q * 8]);
#pragma unroll
        for (int t = 0; t < 4; ++t) {
            bf16x8 bf = *reinterpret_cast<const bf16x8*>(&Bh[(t * 16 + l16) * LP + q * 8]);
            acc[t] = __builtin_amdgcn_mfma_f32_16x16x32_bf16(af, bf, acc[t], 0, 0, 0);
        }
        __syncthreads();
    }
#pragma unroll
    for (int t = 0; t < 4; ++t) {
        const int col = n0 + t * 16 + l16;
        const float bb = bias[col];
#pragma unroll
        for (int r = 0; r < 4; ++r) {
            const int row = m0 + wv * 16 + q * 4 + r;
            C[(size_t)row * N + col] = (bf16)(acc[t][r] + bb);
        }
    }
}

// ---- fused scores + softmax, scores register-resident, split-precision QK ----
// One WG per (16 q-rows, batch). Wave wv owns score cols [wv*256, wv*256+256).
__global__ __launch_bounds__(256) void scores_softmax(const bf16* __restrict__ Qh,
                                                      const bf16* __restrict__ Ql,
                                                      const bf16* __restrict__ Kh,
                                                      const bf16* __restrict__ Kl,
                                                      float* __restrict__ Wout) {
    __shared__ alignas(16) bf16 Qhs[16 * 136];
    __shared__ alignas(16) bf16 Qls[16 * 136];
    __shared__ float redm[4][16];
    __shared__ float reds[4][16];

    const int tid = threadIdx.x;
    const int wv = tid >> 6, ln = tid & 63, q = ln >> 4, l16 = ln & 15;
    const int nb = blockIdx.x;
    const int b  = blockIdx.y;

    {   // stage Q hi/lo tiles [16][128]
        int r = tid >> 4, c = (tid & 15) * 8;
        size_t g = ((size_t)(b * NQ + nb * 16 + r)) * DQK + c;
        *reinterpret_cast<bf16x8*>(&Qhs[r * 136 + c]) = *reinterpret_cast<const bf16x8*>(Qh + g);
        *reinterpret_cast<bf16x8*>(&Qls[r * 136 + c]) = *reinterpret_cast<const bf16x8*>(Ql + g);
    }
    __syncthreads();

    const bf16* Khb = Kh + (size_t)b * MK * DQK;
    const bf16* Klb = Kl + (size_t)b * MK * DQK;

    f32x4 accs[16];
#pragma unroll
    for (int i = 0; i < 16; ++i) accs[i] = (f32x4){0, 0, 0, 0};

#pragma unroll
    for (int i = 0; i < 16; ++i) {
        const int ct = wv * 16 + i;
        const size_t krow = (size_t)(ct * 16 + l16) * DQK;
#pragma unroll
        for (int kk = 0; kk < 4; ++kk) {
            bf16x8 afh = *reinterpret_cast<const bf16x8*>(&Qhs[l16 * 136 + kk * 32 + q * 8]);
            bf16x8 afl = *reinterpret_cast<const bf16x8*>(&Qls[l16 * 136 + kk * 32 + q * 8]);
            bf16x8 bfh = *reinterpret_cast<const bf16x8*>(Khb + krow + kk * 32 + q * 8);
            bf16x8 bfl = *reinterpret_cast<const bf16x8*>(Klb + krow + kk * 32 + q * 8);
            accs[i] = __builtin_amdgcn_mfma_f32_16x16x32_bf16(afh, bfh, accs[i], 0, 0, 0);
            accs[i] = __builtin_amdgcn_mfma_f32_16x16x32_bf16(afh, bfl, accs[i], 0, 0, 0);
            accs[i] = __builtin_amdgcn_mfma_f32_16x16x32_bf16(afl, bfh, accs[i], 0, 0, 0);
        }
    }

    // lane holds rows q*4+r (r=0..3), cols (wv*16+i)*16+l16. Row max:
    float mx[4], sm[4];
#pragma unroll
    for (int r = 0; r < 4; ++r) {
        float m = accs[0][r];
#pragma unroll
        for (int i = 1; i < 16; ++i) m = fmaxf(m, accs[i][r]);
#pragma unroll
        for (int off = 1; off < 16; off <<= 1) m = fmaxf(m, __shfl_xor(m, off, 64));
        mx[r] = m;
    }
    if (l16 == 0) {
#pragma unroll
        for (int r = 0; r < 4; ++r) redm[wv][q * 4 + r] = mx[r];
    }
    __syncthreads();
#pragma unroll
    for (int r = 0; r < 4; ++r) {
        float m = redm[0][q * 4 + r];
#pragma unroll
        for (int w = 1; w < 4; ++w) m = fmaxf(m, redm[w][q * 4 + r]);
        mx[r] = m;
        sm[r] = 0.f;
    }
#pragma unroll
    for (int i = 0; i < 16; ++i)
#pragma unroll
        for (int r = 0; r < 4; ++r) {
            float e = __expf(accs[i][r] - mx[r]);
            accs[i][r] = e;
            sm[r] += e;
        }
#pragma unroll
    for (int r = 0; r < 4; ++r) {
        float s = sm[r];
#pragma unroll
        for (int off = 1; off < 16; off <<= 1) s += __shfl_xor(s, off, 64);
        sm[r] = s;
    }
    if (l16 == 0) {
#pragma unroll
        for (int r = 0; r < 4; ++r) reds[wv][q * 4 + r] = sm[r];
    }
    __syncthreads();
    float inv[4];
#pragma unroll
    for (int r = 0; r < 4; ++r) {
        float s = reds[0][q * 4 + r] + reds[1][q * 4 + r] + reds[2][q * 4 + r] + reds[3][q * 4 + r];
        inv[r] = 1.f / s;
    }
    const size_t rowbase = (size_t)b * NQ + nb * 16;
#pragma unroll
    for (int i = 0; i < 16; ++i) {
        const int col = (wv * 16 + i) * 16 + l16;
#pragma unroll
        for (int r = 0; r < 4; ++r)
            Wout[(rowbase + q * 4 + r) * MK + col] = accs[i][r] * inv[r];
    }
}

// ---- attended + residual: Out[n][d] = sum_m W[n][m]*V[m][d] + X[n][d], fp32 out ----
__global__ __launch_bounds__(256) void attn_out(const float* __restrict__ W,
                                                const bf16* __restrict__ V,
                                                const float* __restrict__ X,
                                                float* __restrict__ Out) {
    __shared__ alignas(16) bf16 Al[64 * LP];
    __shared__ alignas(16) bf16 Bl[64 * LP];
    const int tid = threadIdx.x;
    const int wv = tid >> 6, ln = tid & 63, q = ln >> 4, l16 = ln & 15;
    const int b = blockIdx.z;
    const size_t bo = (size_t)b << 20;
    const int m0 = blockIdx.x * 64;
    const int n0 = blockIdx.y * 64;
    const int ar = tid >> 2, ac = (tid & 3) * 8;
    const int bk = tid >> 3, bn = (tid & 7) * 8;

    f32x4 acc[4] = {{0,0,0,0},{0,0,0,0},{0,0,0,0},{0,0,0,0}};

    for (int k0 = 0; k0 < MK; k0 += 32) {
        const float* wp = W + bo + (size_t)(m0 + ar) * MK + k0 + ac;
        f32x4 w0 = *reinterpret_cast<const f32x4*>(wp);
        f32x4 w1 = *reinterpret_cast<const f32x4*>(wp + 4);
        bf16x8 wv8;
#pragma unroll
        for (int e = 0; e < 8; ++e) wv8[e] = (bf16)((e < 4) ? w0[e] : w1[e - 4]);
        *reinterpret_cast<bf16x8*>(&Al[ar * LP + ac]) = wv8;
        // transpose V tile into Bl[d_local][m_local]
        bf16x8 v8 = *reinterpret_cast<const bf16x8*>(V + bo + (size_t)(k0 + bk) * DIM + n0 + bn);
#pragma unroll
        for (int e = 0; e < 8; ++e) Bl[(bn + e) * LP + bk] = v8[e];
        __syncthreads();
        bf16x8 af = *reinterpret_cast<const bf16x8*>(&Al[(wv * 16 + l16) * LP + q * 8]);
#pragma unroll
        for (int t = 0; t < 4; ++t) {
            bf16x8 bf = *reinterpret_cast<const bf16x8*>(&Bl[(t * 16 + l16) * LP + q * 8]);
            acc[t] = __builtin_amdgcn_mfma_f32_16x16x32_bf16(af, bf, acc[t], 0, 0, 0);
        }
        __syncthreads();
    }
#pragma unroll
    for (int t = 0; t < 4; ++t) {
        const int col = n0 + t * 16 + l16;
#pragma unroll
        for (int r = 0; r < 4; ++r) {
            const int row = m0 + wv * 16 + q * 4 + r;
            const size_t idx = bo + (size_t)row * DIM + col;
            Out[idx] = acc[t][r] + X[idx];
        }
    }
}

extern "C" void kernel_launch(void* const* d_in, const int* in_sizes, int n_in,
                              void* d_out, int out_size, void* d_ws, size_t ws_size,
                              hipStream_t stream) {
    const float* x   = (const float*)d_in[0];   // [32,1024,1024]
    const float* ctx = (const float*)d_in[1];   // [32,1024,1024]
    const float* Wq  = (const float*)d_in[2];   // [1024,128]
    const float* bq  = (const float*)d_in[3];   // [128]
    const float* Wk  = (const float*)d_in[4];   // [1024,128]
    const float* bk  = (const float*)d_in[5];   // [128]
    const float* Wv  = (const float*)d_in[6];   // [1024,1024]
    const float* bv  = (const float*)d_in[7];   // [1024]

    float* out0 = (float*)d_out;                        // attended + x
    float* out1 = out0 + (size_t)BATCH * NQ * DIM;      // weights (fp32)

    // workspace carve-up (bf16): ~99 MB
    bf16* wqTh = (bf16*)d_ws;
    bf16* wqTl = wqTh + (size_t)DQK * DIM;
    bf16* wkTh = wqTl + (size_t)DQK * DIM;
    bf16* wkTl = wkTh + (size_t)DQK * DIM;
    bf16* wvT  = wkTl + (size_t)DQK * DIM;
    bf16* Qhi  = wvT  + (size_t)DIM * DIM;
    bf16* Qlo  = Qhi  + (size_t)BATCH * NQ * DQK;
    bf16* Khi  = Qlo  + (size_t)BATCH * NQ * DQK;
    bf16* Klo  = Khi  + (size_t)BATCH * MK * DQK;
    bf16* Vs   = Klo  + (size_t)BATCH * MK * DQK;       // [32*1024][1024]

    transpose_split<<<(DIM * DQK + 255) / 256, 256, 0, stream>>>(Wq, wqTh, wqTl, DIM, DQK);
    transpose_split<<<(DIM * DQK + 255) / 256, 256, 0, stream>>>(Wk, wkTh, wkTl, DIM, DQK);
    transpose_cvt<<<(DIM * DIM + 255) / 256, 256, 0, stream>>>(Wv, wvT, DIM, DIM);

    gemm_bt_split<<<dim3((BATCH * NQ) / 64, DQK / 64), 256, 0, stream>>>(
        x, wqTh, wqTl, bq, Qhi, Qlo, BATCH * NQ, DQK, DIM);
    gemm_bt_split<<<dim3((BATCH * MK) / 64, DQK / 64), 256, 0, stream>>>(
        ctx, wkTh, wkTl, bk, Khi, Klo, BATCH * MK, DQK, DIM);
    gemm_bt_plain<<<dim3((BATCH * MK) / 64, DIM / 64), 256, 0, stream>>>(
        ctx, wvT, bv, Vs, BATCH * MK, DIM, DIM);

    scores_softmax<<<dim3(NQ / 16, BATCH), 256, 0, stream>>>(Qhi, Qlo, Khi, Klo, out1);

    attn_out<<<dim3(NQ / 64, DIM / 64, BATCH), 256, 0, stream>>>(out1, Vs, x, out0);
}

// Round 3
// 1009.716 us; speedup vs baseline: 1.2423x; 1.2423x over previous
//
#include <hip/hip_runtime.h>

using bf16   = __bf16;
using bf16x8 = __attribute__((ext_vector_type(8))) __bf16;
using f32x4  = __attribute__((ext_vector_type(4))) float;

constexpr int BATCH = 32;
constexpr int NQ    = 1024;
constexpr int MK    = 1024;
constexpr int DIM   = 1024;
constexpr int DQK   = 128;
constexpr int LP    = 40;   // padded LDS pitch for the 64-tile kernels

// async 16B global -> LDS (dest = wave-uniform base + lane*16)
__device__ __forceinline__ void gll16(const bf16* g, bf16* l) {
    __builtin_amdgcn_global_load_lds((const __attribute__((address_space(1))) void*)g,
                                     (__attribute__((address_space(3))) void*)l, 16, 0, 0);
}

// ---- fp32 -> bf16 convert (8 elems/thread) ----
__global__ void cvt_bf16(const float* __restrict__ in, bf16* __restrict__ out, int n) {
    int i = (blockIdx.x * 256 + threadIdx.x) * 8;
    if (i >= n) return;
    f32x4 a = *reinterpret_cast<const f32x4*>(in + i);
    f32x4 b = *reinterpret_cast<const f32x4*>(in + i + 4);
    bf16x8 o;
#pragma unroll
    for (int e = 0; e < 4; ++e) { o[e] = (bf16)a[e]; o[e + 4] = (bf16)b[e]; }
    *reinterpret_cast<bf16x8*>(out + i) = o;
}

// ---- weight transpose + bf16 split ----
__global__ void transpose_split(const float* __restrict__ in, bf16* __restrict__ hiT,
                                bf16* __restrict__ loT, int R, int C) {
    int idx = blockIdx.x * 256 + threadIdx.x;
    if (idx >= R * C) return;
    int r = idx / C, c = idx - r * C;
    float v = in[idx];
    bf16 h = (bf16)v;
    hiT[(size_t)c * R + r] = h;
    loT[(size_t)c * R + r] = (bf16)(v - (float)h);
}

__global__ void transpose_cvt(const float* __restrict__ in, bf16* __restrict__ outT,
                              int R, int C) {
    int idx = blockIdx.x * 256 + threadIdx.x;
    if (idx >= R * C) return;
    int r = idx / C, c = idx - r * C;
    outT[(size_t)c * R + r] = (bf16)in[idx];
}

// ---- split-precision GEMM (Q/K proj): C = A(fp32)*BT^T + bias -> bf16 hi+lo ----
__global__ __launch_bounds__(256) void gemm_bt_split(const float* __restrict__ A,
                                                     const bf16* __restrict__ BhT,
                                                     const bf16* __restrict__ BlT,
                                                     const float* __restrict__ bias,
                                                     bf16* __restrict__ Chi,
                                                     bf16* __restrict__ Clo,
                                                     int M, int N, int K) {
    __shared__ alignas(16) bf16 Ah[64 * LP];
    __shared__ alignas(16) bf16 Al[64 * LP];
    __shared__ alignas(16) bf16 Bh[64 * LP];
    __shared__ alignas(16) bf16 Bl[64 * LP];
    const int tid = threadIdx.x;
    const int wv = tid >> 6, ln = tid & 63, q = ln >> 4, l16 = ln & 15;
    const int m0 = blockIdx.x * 64, n0 = blockIdx.y * 64;
    const int sr = tid >> 2, sc = (tid & 3) * 8;

    f32x4 acc[4] = {{0,0,0,0},{0,0,0,0},{0,0,0,0},{0,0,0,0}};

    for (int k0 = 0; k0 < K; k0 += 32) {
        const float* ap = A + (size_t)(m0 + sr) * K + k0 + sc;
        f32x4 a0 = *reinterpret_cast<const f32x4*>(ap);
        f32x4 a1 = *reinterpret_cast<const f32x4*>(ap + 4);
        bf16x8 hv, lv;
#pragma unroll
        for (int e = 0; e < 8; ++e) {
            float v = (e < 4) ? a0[e] : a1[e - 4];
            bf16 h = (bf16)v;
            hv[e] = h;
            lv[e] = (bf16)(v - (float)h);
        }
        *reinterpret_cast<bf16x8*>(&Ah[sr * LP + sc]) = hv;
        *reinterpret_cast<bf16x8*>(&Al[sr * LP + sc]) = lv;
        *reinterpret_cast<bf16x8*>(&Bh[sr * LP + sc]) =
            *reinterpret_cast<const bf16x8*>(BhT + (size_t)(n0 + sr) * K + k0 + sc);
        *reinterpret_cast<bf16x8*>(&Bl[sr * LP + sc]) =
            *reinterpret_cast<const bf16x8*>(BlT + (size_t)(n0 + sr) * K + k0 + sc);
        __syncthreads();
        bf16x8 afh = *reinterpret_cast<const bf16x8*>(&Ah[(wv * 16 + l16) * LP + q * 8]);
        bf16x8 afl = *reinterpret_cast<const bf16x8*>(&Al[(wv * 16 + l16) * LP + q * 8]);
#pragma unroll
        for (int t = 0; t < 4; ++t) {
            bf16x8 bfh = *reinterpret_cast<const bf16x8*>(&Bh[(t * 16 + l16) * LP + q * 8]);
            bf16x8 bfl = *reinterpret_cast<const bf16x8*>(&Bl[(t * 16 + l16) * LP + q * 8]);
            acc[t] = __builtin_amdgcn_mfma_f32_16x16x32_bf16(afh, bfh, acc[t], 0, 0, 0);
            acc[t] = __builtin_amdgcn_mfma_f32_16x16x32_bf16(afh, bfl, acc[t], 0, 0, 0);
            acc[t] = __builtin_amdgcn_mfma_f32_16x16x32_bf16(afl, bfh, acc[t], 0, 0, 0);
        }
        __syncthreads();
    }
#pragma unroll
    for (int t = 0; t < 4; ++t) {
        const int col = n0 + t * 16 + l16;
        const float bb = bias[col];
#pragma unroll
        for (int r = 0; r < 4; ++r) {
            const int row = m0 + wv * 16 + q * 4 + r;
            float v = acc[t][r] + bb;
            bf16 h = (bf16)v;
            Chi[(size_t)row * N + col] = h;
            Clo[(size_t)row * N + col] = (bf16)(v - (float)h);
        }
    }
}

// ---- m97-style 128x128 bf16 GEMM: VT = WvT * ctx_bf^T, bias by ROW, bf16 out ----
// D[d][j] = sum_k WvT[d][k] * ctxb[j][k] + bv[d];  out row stride 32768.
__global__ __launch_bounds__(256) void vproj_vt(const bf16* __restrict__ Aw,
                                                const bf16* __restrict__ Bc,
                                                const float* __restrict__ bv,
                                                bf16* __restrict__ VT) {
    __shared__ alignas(16) bf16 At[128 * 32];
    __shared__ alignas(16) bf16 Bt[128 * 32];
    const int tid = threadIdx.x;
    const int w = tid >> 6, ln = tid & 63, q = ln >> 4, l16 = ln & 15;
    const int wm = w >> 1, wn = w & 1;
    const int m0 = blockIdx.x * 128;           // d block (0..7)
    const int n0 = blockIdx.y * 128;           // ctx-row block (0..255)
    const int lrow = ln >> 2, lk = (ln & 3) * 8;

    f32x4 acc[4][4] = {};

    for (int k0 = 0; k0 < DIM; k0 += 32) {
#pragma unroll
        for (int j = 0; j < 2; ++j) {
            const int row = (w * 2 + j) * 16 + lrow;
            gll16(Aw + (size_t)(m0 + row) * DIM + k0 + lk, &At[(w * 2 + j) * 512]);
            gll16(Bc + (size_t)(n0 + row) * DIM + k0 + lk, &Bt[(w * 2 + j) * 512]);
        }
        __syncthreads();
        bf16x8 af[4], bfr[4];
#pragma unroll
        for (int i = 0; i < 4; ++i)
            af[i] = *reinterpret_cast<const bf16x8*>(&At[(wm * 64 + i * 16 + l16) * 32 + q * 8]);
#pragma unroll
        for (int j = 0; j < 4; ++j)
            bfr[j] = *reinterpret_cast<const bf16x8*>(&Bt[(wn * 64 + j * 16 + l16) * 32 + q * 8]);
#pragma unroll
        for (int i = 0; i < 4; ++i)
#pragma unroll
            for (int j = 0; j < 4; ++j)
                acc[i][j] = __builtin_amdgcn_mfma_f32_16x16x32_bf16(af[i], bfr[j], acc[i][j], 0, 0, 0);
        __syncthreads();
    }
#pragma unroll
    for (int i = 0; i < 4; ++i)
#pragma unroll
        for (int r = 0; r < 4; ++r) {
            const int row = m0 + wm * 64 + i * 16 + q * 4 + r;
            const float bb = bv[row];
#pragma unroll
            for (int j = 0; j < 4; ++j) {
                const int col = n0 + wn * 64 + j * 16 + l16;
                VT[(size_t)row * (BATCH * MK) + col] = (bf16)(acc[i][j][r] + bb);
            }
        }
}

// ---- m97-style 128x128 bf16 GEMM: Out = Wbf * VT^T + X (fp32 out) ----
// rows = b*1024 + q (32768), cols = d (1024). B row stride 32768, col offset b*1024.
__global__ __launch_bounds__(256) void attn_out_128(const bf16* __restrict__ Wbf,
                                                    const bf16* __restrict__ VT,
                                                    const float* __restrict__ X,
                                                    float* __restrict__ Out) {
    __shared__ alignas(16) bf16 At[128 * 32];
    __shared__ alignas(16) bf16 Bt[128 * 32];
    const int tid = threadIdx.x;
    const int w = tid >> 6, ln = tid & 63, q = ln >> 4, l16 = ln & 15;
    const int wm = w >> 1, wn = w & 1;
    const int mb = blockIdx.x;                 // 0..255
    const int m0 = mb * 128;
    const int n0 = blockIdx.y * 128;           // d block (0..7)
    const int b  = mb >> 3;
    const int lrow = ln >> 2, lk = (ln & 3) * 8;
    const bf16* Bb = VT + (size_t)b * MK;      // column offset within VT rows

    f32x4 acc[4][4] = {};

    for (int k0 = 0; k0 < MK; k0 += 32) {
#pragma unroll
        for (int j = 0; j < 2; ++j) {
            const int row = (w * 2 + j) * 16 + lrow;
            gll16(Wbf + (size_t)(m0 + row) * MK + k0 + lk, &At[(w * 2 + j) * 512]);
            gll16(Bb + (size_t)(n0 + row) * (BATCH * MK) + k0 + lk, &Bt[(w * 2 + j) * 512]);
        }
        __syncthreads();
        bf16x8 af[4], bfr[4];
#pragma unroll
        for (int i = 0; i < 4; ++i)
            af[i] = *reinterpret_cast<const bf16x8*>(&At[(wm * 64 + i * 16 + l16) * 32 + q * 8]);
#pragma unroll
        for (int j = 0; j < 4; ++j)
            bfr[j] = *reinterpret_cast<const bf16x8*>(&Bt[(wn * 64 + j * 16 + l16) * 32 + q * 8]);
#pragma unroll
        for (int i = 0; i < 4; ++i)
#pragma unroll
            for (int j = 0; j < 4; ++j)
                acc[i][j] = __builtin_amdgcn_mfma_f32_16x16x32_bf16(af[i], bfr[j], acc[i][j], 0, 0, 0);
        __syncthreads();
    }
#pragma unroll
    for (int i = 0; i < 4; ++i)
#pragma unroll
        for (int j = 0; j < 4; ++j) {
            const int col = n0 + wn * 64 + j * 16 + l16;
#pragma unroll
            for (int r = 0; r < 4; ++r) {
                const int row = m0 + wm * 64 + i * 16 + q * 4 + r;
                const size_t idx = (size_t)row * DIM + col;
                Out[idx] = acc[i][j][r] + X[idx];
            }
        }
}

// ---- fused scores + softmax (register-resident, split QK); fp32 + bf16 outputs ----
__global__ __launch_bounds__(256) void scores_softmax(const bf16* __restrict__ Qh,
                                                      const bf16* __restrict__ Ql,
                                                      const bf16* __restrict__ Kh,
                                                      const bf16* __restrict__ Kl,
                                                      float* __restrict__ Wout,
                                                      bf16* __restrict__ Wbf) {
    __shared__ alignas(16) bf16 Qhs[16 * 136];
    __shared__ alignas(16) bf16 Qls[16 * 136];
    __shared__ float redm[4][16];
    __shared__ float reds[4][16];

    const int tid = threadIdx.x;
    const int wv = tid >> 6, ln = tid & 63, q = ln >> 4, l16 = ln & 15;
    const int nb = blockIdx.x;
    const int b  = blockIdx.y;

    {
        int r = tid >> 4, c = (tid & 15) * 8;
        size_t g = ((size_t)(b * NQ + nb * 16 + r)) * DQK + c;
        *reinterpret_cast<bf16x8*>(&Qhs[r * 136 + c]) = *reinterpret_cast<const bf16x8*>(Qh + g);
        *reinterpret_cast<bf16x8*>(&Qls[r * 136 + c]) = *reinterpret_cast<const bf16x8*>(Ql + g);
    }
    __syncthreads();

    const bf16* Khb = Kh + (size_t)b * MK * DQK;
    const bf16* Klb = Kl + (size_t)b * MK * DQK;

    f32x4 accs[16];
#pragma unroll
    for (int i = 0; i < 16; ++i) accs[i] = (f32x4){0, 0, 0, 0};

#pragma unroll
    for (int i = 0; i < 16; ++i) {
        const int ct = wv * 16 + i;
        const size_t krow = (size_t)(ct * 16 + l16) * DQK;
#pragma unroll
        for (int kk = 0; kk < 4; ++kk) {
            bf16x8 afh = *reinterpret_cast<const bf16x8*>(&Qhs[l16 * 136 + kk * 32 + q * 8]);
            bf16x8 afl = *reinterpret_cast<const bf16x8*>(&Qls[l16 * 136 + kk * 32 + q * 8]);
            bf16x8 bfh = *reinterpret_cast<const bf16x8*>(Khb + krow + kk * 32 + q * 8);
            bf16x8 bfl = *reinterpret_cast<const bf16x8*>(Klb + krow + kk * 32 + q * 8);
            accs[i] = __builtin_amdgcn_mfma_f32_16x16x32_bf16(afh, bfh, accs[i], 0, 0, 0);
            accs[i] = __builtin_amdgcn_mfma_f32_16x16x32_bf16(afh, bfl, accs[i], 0, 0, 0);
            accs[i] = __builtin_amdgcn_mfma_f32_16x16x32_bf16(afl, bfh, accs[i], 0, 0, 0);
        }
    }

    float mx[4], sm[4];
#pragma unroll
    for (int r = 0; r < 4; ++r) {
        float m = accs[0][r];
#pragma unroll
        for (int i = 1; i < 16; ++i) m = fmaxf(m, accs[i][r]);
#pragma unroll
        for (int off = 1; off < 16; off <<= 1) m = fmaxf(m, __shfl_xor(m, off, 64));
        mx[r] = m;
    }
    if (l16 == 0) {
#pragma unroll
        for (int r = 0; r < 4; ++r) redm[wv][q * 4 + r] = mx[r];
    }
    __syncthreads();
#pragma unroll
    for (int r = 0; r < 4; ++r) {
        float m = redm[0][q * 4 + r];
#pragma unroll
        for (int wq = 1; wq < 4; ++wq) m = fmaxf(m, redm[wq][q * 4 + r]);
        mx[r] = m;
        sm[r] = 0.f;
    }
#pragma unroll
    for (int i = 0; i < 16; ++i)
#pragma unroll
        for (int r = 0; r < 4; ++r) {
            float e = __expf(accs[i][r] - mx[r]);
            accs[i][r] = e;
            sm[r] += e;
        }
#pragma unroll
    for (int r = 0; r < 4; ++r) {
        float s = sm[r];
#pragma unroll
        for (int off = 1; off < 16; off <<= 1) s += __shfl_xor(s, off, 64);
        sm[r] = s;
    }
    if (l16 == 0) {
#pragma unroll
        for (int r = 0; r < 4; ++r) reds[wv][q * 4 + r] = sm[r];
    }
    __syncthreads();
    float inv[4];
#pragma unroll
    for (int r = 0; r < 4; ++r)
        inv[r] = 1.f / (reds[0][q * 4 + r] + reds[1][q * 4 + r] +
                        reds[2][q * 4 + r] + reds[3][q * 4 + r]);
    const size_t rowbase = (size_t)b * NQ + nb * 16;
#pragma unroll
    for (int i = 0; i < 16; ++i) {
        const int col = (wv * 16 + i) * 16 + l16;
#pragma unroll
        for (int r = 0; r < 4; ++r) {
            const float v = accs[i][r] * inv[r];
            const size_t idx = (rowbase + q * 4 + r) * MK + col;
            Wout[idx] = v;
            Wbf[idx]  = (bf16)v;
        }
    }
}

extern "C" void kernel_launch(void* const* d_in, const int* in_sizes, int n_in,
                              void* d_out, int out_size, void* d_ws, size_t ws_size,
                              hipStream_t stream) {
    const float* x   = (const float*)d_in[0];
    const float* ctx = (const float*)d_in[1];
    const float* Wq  = (const float*)d_in[2];
    const float* bq  = (const float*)d_in[3];
    const float* Wk  = (const float*)d_in[4];
    const float* bk  = (const float*)d_in[5];
    const float* Wv  = (const float*)d_in[6];
    const float* bv  = (const float*)d_in[7];

    float* out0 = (float*)d_out;
    float* out1 = out0 + (size_t)BATCH * NQ * DIM;

    // workspace carve-up (bf16), ~238 MB
    bf16* wqTh = (bf16*)d_ws;
    bf16* wqTl = wqTh + (size_t)DQK * DIM;
    bf16* wkTh = wqTl + (size_t)DQK * DIM;
    bf16* wkTl = wkTh + (size_t)DQK * DIM;
    bf16* wvT  = wkTl + (size_t)DQK * DIM;
    bf16* Qhi  = wvT  + (size_t)DIM * DIM;
    bf16* Qlo  = Qhi  + (size_t)BATCH * NQ * DQK;
    bf16* Khi  = Qlo  + (size_t)BATCH * NQ * DQK;
    bf16* Klo  = Khi  + (size_t)BATCH * MK * DQK;
    bf16* VT   = Klo  + (size_t)BATCH * MK * DQK;       // [1024][32768]
    bf16* ctxb = VT   + (size_t)DIM * BATCH * MK;       // [32768][1024]
    bf16* Wbf  = ctxb + (size_t)BATCH * MK * DIM;       // [32768][1024]

    transpose_split<<<(DIM * DQK + 255) / 256, 256, 0, stream>>>(Wq, wqTh, wqTl, DIM, DQK);
    transpose_split<<<(DIM * DQK + 255) / 256, 256, 0, stream>>>(Wk, wkTh, wkTl, DIM, DQK);
    transpose_cvt<<<(DIM * DIM + 255) / 256, 256, 0, stream>>>(Wv, wvT, DIM, DIM);
    cvt_bf16<<<(BATCH * MK * DIM / 8 + 255) / 256, 256, 0, stream>>>(
        ctx, ctxb, BATCH * MK * DIM);

    gemm_bt_split<<<dim3((BATCH * NQ) / 64, DQK / 64), 256, 0, stream>>>(
        x, wqTh, wqTl, bq, Qhi, Qlo, BATCH * NQ, DQK, DIM);
    gemm_bt_split<<<dim3((BATCH * MK) / 64, DQK / 64), 256, 0, stream>>>(
        ctx, wkTh, wkTl, bk, Khi, Klo, BATCH * MK, DQK, DIM);

    vproj_vt<<<dim3(DIM / 128, (BATCH * MK) / 128), 256, 0, stream>>>(wvT, ctxb, bv, VT);

    scores_softmax<<<dim3(NQ / 16, BATCH), 256, 0, stream>>>(Qhi, Qlo, Khi, Klo, out1, Wbf);

    attn_out_128<<<dim3((BATCH * NQ) / 128, DIM / 128), 256, 0, stream>>>(Wbf, VT, x, out0);
}